// Round 7
// baseline (253.089 us; speedup 1.0000x reference)
//
#include <hip/hip_runtime.h>
#include <stdint.h>

#define D_DIM 2048
#define OUT_DIM 2048
#define NTOK 16384
#define SCALING 1.0f
#define NT_TILES 34   // 32 K-tiles of x@W^T + 2 LoRA-extension tiles

typedef unsigned short u16;
typedef __attribute__((ext_vector_type(8))) short s16x8;
typedef __attribute__((ext_vector_type(4))) float f32x4;

// ws layout (bytes)
#define WZ_OFF  0u           // W bf16 swizzled [2048 o][2048 d]
#define AZ_OFF  8388608u     // experts_A^T bf16 swizzled [128 er][2048 d]
#define BZ_OFF  8912896u     // experts_B^T bf16 swizzled [2048 o][128 er]
#define CZ_OFF  9437184u     // c bf16 swizzled [16384 t][128 er]
#define W8_OFF  13631488u    // router weights f32 [16384][8]
#define XB_OFF  14155776u    // x bf16 swizzled [16384][2048]
#define WS_BIG   81264640u

__device__ inline u16 f2bf(float f) {
  union { float f; uint32_t u; } v; v.f = f;
  uint32_t u = v.u;
  u += 0x7FFFu + ((u >> 16) & 1u);   // round-to-nearest-even
  return (u16)(u >> 16);
}

// ---- merged prep + router: cast/swizzle W,A^T,B^T; router logits + xb cast ---
__global__ __launch_bounds__(256) void k_prep_router(
    const float* __restrict__ W, const float* __restrict__ A,
    const float* __restrict__ Bf, const float* __restrict__ x,
    const float* __restrict__ rw,
    u16* __restrict__ Wz, u16* __restrict__ Az, u16* __restrict__ Bz,
    float* __restrict__ w8, u16* __restrict__ xb) {
  int bid = blockIdx.x;
  if (bid < 4096) {                      // W: 2048x2048 f32 -> bf16 swizzled
    int idx = bid * 256 + threadIdx.x;
    int o  = idx >> 9;
    int k0 = (idx & 511) * 4;
    const float4 v = *(const float4*)&W[(size_t)o * D_DIM + k0];
    int s = (o & 7) << 3;
    int dst = (k0 & ~63) | ((k0 & 63) ^ s);
    uint32_t p0 = (uint32_t)f2bf(v.x) | ((uint32_t)f2bf(v.y) << 16);
    uint32_t p1 = (uint32_t)f2bf(v.z) | ((uint32_t)f2bf(v.w) << 16);
    *(uint2*)&Wz[(size_t)o * D_DIM + dst] = make_uint2(p0, p1);
    return;
  }
  if (bid < 5120) {                      // experts_A -> A^T swizzled
    int idx = (bid - 4096) * 256 + threadIdx.x;
    float v = A[idx];
    int r = idx & 15;
    int d = (idx >> 4) & 2047;
    int e = idx >> 15;
    int er = e * 16 + r;
    int s = (er & 7) << 3;
    int dst = (d & ~63) | ((d & 63) ^ s);
    Az[(size_t)er * D_DIM + dst] = f2bf(v);
    return;
  }
  if (bid < 6144) {                      // experts_B -> B^T swizzled
    int idx = (bid - 5120) * 256 + threadIdx.x;
    float v = Bf[idx];
    int er = idx >> 11;
    int o  = idx & 2047;
    int s = (o & 7) << 3;
    int dst = (er & 64) | ((er & 63) ^ s);
    Bz[(size_t)o * 128 + dst] = f2bf(v);
    return;
  }
  // router + xb precast: one wave per token
  int lane = threadIdx.x & 63, wid = threadIdx.x >> 6;
  int t = (bid - 6144) * 4 + wid;
  const float* xr = x + (size_t)t * D_DIM;
  float4 xv[8];
#pragma unroll
  for (int j = 0; j < 8; ++j) xv[j] = *(const float4*)&xr[j * 256 + lane * 4];
  int s = (t & 7) << 3;
#pragma unroll
  for (int j = 0; j < 8; ++j) {
    int c4 = j * 256 + lane * 4;
    int dst = (c4 & ~63) | ((c4 & 63) ^ s);
    uint32_t p0 = (uint32_t)f2bf(xv[j].x) | ((uint32_t)f2bf(xv[j].y) << 16);
    uint32_t p1 = (uint32_t)f2bf(xv[j].z) | ((uint32_t)f2bf(xv[j].w) << 16);
    *(uint2*)&xb[(size_t)t * D_DIM + dst] = make_uint2(p0, p1);
  }
  float lg[8];
#pragma unroll
  for (int e = 0; e < 8; ++e) {
    float a = 0.f;
#pragma unroll
    for (int j = 0; j < 8; ++j) {
      float4 rv = *(const float4*)&rw[e * D_DIM + j * 256 + lane * 4];
      a = fmaf(xv[j].x, rv.x, a); a = fmaf(xv[j].y, rv.y, a);
      a = fmaf(xv[j].z, rv.z, a); a = fmaf(xv[j].w, rv.w, a);
    }
#pragma unroll
    for (int off = 32; off; off >>= 1) a += __shfl_xor(a, off, 64);
    lg[e] = a;
  }
  int i0 = 0;
#pragma unroll
  for (int e = 1; e < 8; ++e) if (lg[e] > lg[i0]) i0 = e;
  int i1 = (i0 == 0) ? 1 : 0;
#pragma unroll
  for (int e = 0; e < 8; ++e) if (e != i0 && lg[e] > lg[i1]) i1 = e;
  float e1 = expf(lg[i1] - lg[i0]);
  float inv = 1.f / (1.f + e1);
  float w0 = inv * SCALING, w1 = e1 * inv * SCALING;
  if (lane < 8)
    w8[(size_t)t * 8 + lane] = (lane == i0) ? w0 : (lane == i1) ? w1 : 0.f;
}

// ---------------- lora-down: c = (xb @ A_all) * w8 -> Cz (M-tile 64) ----------
__global__ __launch_bounds__(256) void k_lora64(const u16* __restrict__ xb,
                                                const u16* __restrict__ Az,
                                                const float* __restrict__ w8,
                                                u16* __restrict__ Cz) {
  __shared__ u16 Alds[2][64 * 64];
  __shared__ u16 Blds[2][128 * 64];
  __shared__ float w8s[64 * 8];
  int tid = threadIdx.x, lane = tid & 63, wid = tid >> 6;
  int t0 = blockIdx.x * 64;
  w8s[tid] = w8[(size_t)t0 * 8 + tid];
  w8s[256 + tid] = w8[(size_t)t0 * 8 + 256 + tid];
  f32x4 acc[8];
#pragma unroll
  for (int n = 0; n < 8; ++n) acc[n] = (f32x4){0.f, 0.f, 0.f, 0.f};
  const int ce = (lane >> 4) * 8;

  auto stage = [&](int kc, int buf) {
    if (kc > 31) kc = 31;
#pragma unroll
    for (int i = 0; i < 2; ++i) {
      const u16* g = xb + (size_t)(t0 + i * 32 + (tid >> 3)) * D_DIM + kc * 64 + (tid & 7) * 8;
      __builtin_amdgcn_global_load_lds(
          (const __attribute__((address_space(1))) void*)g,
          (__attribute__((address_space(3))) void*)(&Alds[buf][0] + i * 2048 + tid * 8), 16, 0, 0);
    }
#pragma unroll
    for (int i = 0; i < 4; ++i) {
      const u16* g = Az + (size_t)(i * 32 + (tid >> 3)) * D_DIM + kc * 64 + (tid & 7) * 8;
      __builtin_amdgcn_global_load_lds(
          (const __attribute__((address_space(1))) void*)g,
          (__attribute__((address_space(3))) void*)(&Blds[buf][0] + i * 2048 + tid * 8), 16, 0, 0);
    }
  };

  stage(0, 0);
  asm volatile("s_waitcnt vmcnt(0)" ::: "memory");
  __builtin_amdgcn_s_barrier();
  for (int kc = 0; kc < 32; ++kc) {
    int cur = kc & 1;
    stage(kc + 1, cur ^ 1);
#pragma unroll
    for (int kk = 0; kk < 2; ++kk) {
      int ar = wid * 16 + (lane & 15);
      s16x8 af = *(const s16x8*)&Alds[cur][ar * 64 + ((ce + kk * 32) ^ ((ar & 7) << 3))];
#pragma unroll
      for (int nf = 0; nf < 8; ++nf) {
        int br = nf * 16 + (lane & 15);
        s16x8 bf = *(const s16x8*)&Blds[cur][br * 64 + ((ce + kk * 32) ^ ((br & 7) << 3))];
        acc[nf] = __builtin_amdgcn_mfma_f32_16x16x32_bf16(af, bf, acc[nf], 0, 0, 0);
      }
    }
    asm volatile("s_waitcnt vmcnt(0)" ::: "memory");
    __builtin_amdgcn_s_barrier();
  }
#pragma unroll
  for (int q = 0; q < 4; ++q) {
    int rloc = wid * 16 + (lane >> 4) * 4 + q;
#pragma unroll
    for (int nf = 0; nf < 8; ++nf) {
      int er = nf * 16 + (lane & 15);
      float v = acc[nf][q] * w8s[rloc * 8 + (er >> 4)];
      int dst = (er & 64) | ((er & 63) ^ ((rloc & 7) << 3));
      Cz[(size_t)(t0 + rloc) * 128 + dst] = f2bf(v);
    }
  }
}

// -------- 256^2 main GEMM: 2-phase, depth-2 prefetch, compiler-scheduled ------
__device__ inline void stg(int kt, int h, int t0, int o0,
                           const u16* __restrict__ xb, const u16* __restrict__ Wz,
                           const u16* __restrict__ Cz, const u16* __restrict__ Bz,
                           u16* AshP, u16* BshP, int tid) {
  if (kt >= NT_TILES) kt = NT_TILES - 1;   // tail clamp: same-value rewrite, benign
  int p = kt & 1;
  const u16* src; int ld; size_t r0; int c0; u16* dst;
  if (h < 2) {
    if (kt < 32) { src = xb; ld = D_DIM; c0 = kt * 64; }
    else         { src = Cz; ld = 128;   c0 = (kt - 32) * 64; }
    r0 = (size_t)t0 + h * 128;
    dst = AshP + p * 16384 + h * 8192;
  } else {
    if (kt < 32) { src = Wz; ld = D_DIM; c0 = kt * 64; }
    else         { src = Bz; ld = 128;   c0 = (kt - 32) * 64; }
    r0 = (size_t)o0 + (h - 2) * 128;
    dst = BshP + p * 16384 + (h - 2) * 8192;
  }
#pragma unroll
  for (int i = 0; i < 2; ++i) {
    const u16* g = src + (r0 + i * 64 + (tid >> 3)) * (size_t)ld + c0 + (tid & 7) * 8;
    __builtin_amdgcn_global_load_lds(
        (const __attribute__((address_space(1))) void*)g,
        (__attribute__((address_space(3))) void*)(dst + i * 4096 + tid * 8), 16, 0, 0);
  }
}

__device__ inline void read_af(const u16* buf, int rbase, int ce, s16x8 a[4][2]) {
#pragma unroll
  for (int i = 0; i < 4; ++i)
#pragma unroll
    for (int kk = 0; kk < 2; ++kk) {
      int r = rbase + i * 16;
      a[i][kk] = *(const s16x8*)&buf[r * 64 + ((ce + kk * 32) ^ ((r & 7) << 3))];
    }
}

__device__ inline void read_b4(const u16* buf, int rbase, int ce, s16x8 b[4][2]) {
#pragma unroll
  for (int i = 0; i < 4; ++i)
#pragma unroll
    for (int kk = 0; kk < 2; ++kk) {
      int r = rbase + i * 16;
      b[i][kk] = *(const s16x8*)&buf[r * 64 + ((ce + kk * 32) ^ ((r & 7) << 3))];
    }
}

template <int MFH>
__device__ inline void mfma_half(f32x4 acc[8][4], const s16x8 a[4][2],
                                 const s16x8 b[4][2]) {
#pragma unroll
  for (int i = 0; i < 4; ++i)
#pragma unroll
    for (int j = 0; j < 4; ++j)
#pragma unroll
      for (int kk = 0; kk < 2; ++kk)
        acc[MFH * 4 + i][j] = __builtin_amdgcn_mfma_f32_16x16x32_bf16(
            a[i][kk], b[j][kk], acc[MFH * 4 + i][j], 0, 0, 0);
}

__global__ __launch_bounds__(512, 2) void k_main8(const u16* __restrict__ xb,
                                                  const u16* __restrict__ Wz,
                                                  const u16* __restrict__ Cz,
                                                  const u16* __restrict__ Bz,
                                                  float* __restrict__ out) {
  __shared__ u16 Ash[2][16384];
  __shared__ u16 Bsh[2][16384];
  const int tid = threadIdx.x, lane = tid & 63;
  const int wid = tid >> 6, wm = wid >> 2, wn = wid & 3;
  int bid = blockIdx.x;                     // 512 blocks, 512 % 8 == 0
  int swz = (bid & 7) * 64 + (bid >> 3);    // XCD-aware, bijective
  int mt = swz >> 3, nt = swz & 7;
  int t0 = mt * 256, o0 = nt * 256;
  const int ce = (lane >> 4) * 8;
  const int arb = wm * 128 + (lane & 15);
  const int brb = wn * 64 + (lane & 15);
  u16* A0p = &Ash[0][0];
  u16* B0p = &Bsh[0][0];

  f32x4 acc[8][4];
#pragma unroll
  for (int m = 0; m < 8; ++m)
#pragma unroll
    for (int n = 0; n < 4; ++n) acc[m][n] = (f32x4){0.f, 0.f, 0.f, 0.f};
  s16x8 a[4][2], b[4][2];

#define STG(kt) do { stg(kt, 0, t0, o0, xb, Wz, Cz, Bz, A0p, B0p, tid); \
                     stg(kt, 1, t0, o0, xb, Wz, Cz, Bz, A0p, B0p, tid); \
                     stg(kt, 2, t0, o0, xb, Wz, Cz, Bz, A0p, B0p, tid); \
                     stg(kt, 3, t0, o0, xb, Wz, Cz, Bz, A0p, B0p, tid); } while (0)

  // prologue: stage tile0 + tile1 (16 loads/thread-wave); wait tile0 only
  STG(0);
  STG(1);
  asm volatile("s_waitcnt vmcnt(8)" ::: "memory");
  __builtin_amdgcn_s_barrier();

  for (int kt = 0; kt < NT_TILES; ++kt) {
    const int p = kt & 1;
    const u16* Abuf = A0p + p * 16384;
    const u16* Bbuf = B0p + p * 16384;
    // compute tile kt: compiler interleaves ds_reads with MFMA (fine lgkmcnt)
    read_af(Abuf, arb, ce, a);
    read_b4(Bbuf, brb, ce, b);
    mfma_half<0>(acc, a, b);
    read_af(Abuf, arb + 64, ce, a);
    mfma_half<1>(acc, a, b);
    // buf[p] fully consumed by this wave; sync, then restage it with tile kt+2
    __builtin_amdgcn_s_barrier();
    STG(kt + 2);
    asm volatile("s_waitcnt vmcnt(8)" ::: "memory");  // tile kt+1 landed (per wave)
    __builtin_amdgcn_s_barrier();                      // ... for all waves
  }
  asm volatile("s_waitcnt vmcnt(0) lgkmcnt(0)" ::: "memory");
#undef STG

#pragma unroll
  for (int mf = 0; mf < 8; ++mf)
#pragma unroll
    for (int q = 0; q < 4; ++q) {
      int row = t0 + wm * 128 + mf * 16 + (lane >> 4) * 4 + q;
#pragma unroll
      for (int nf = 0; nf < 4; ++nf) {
        int col = o0 + wn * 64 + nf * 16 + (lane & 15);
        out[(size_t)row * OUT_DIM + col] = acc[mf][nf][q];
      }
    }
}

extern "C" void kernel_launch(void* const* d_in, const int* in_sizes, int n_in,
                              void* d_out, int out_size, void* d_ws, size_t ws_size,
                              hipStream_t stream) {
  const float* x  = (const float*)d_in[0];
  const float* W  = (const float*)d_in[1];
  const float* rw = (const float*)d_in[2];
  const float* eA = (const float*)d_in[3];
  const float* eB = (const float*)d_in[4];
  float* out = (float*)d_out;
  char* ws = (char*)d_ws;
  if (ws_size < WS_BIG) return;

  u16*   Wz = (u16*)(ws + WZ_OFF);
  u16*   Az = (u16*)(ws + AZ_OFF);
  u16*   Bz = (u16*)(ws + BZ_OFF);
  u16*   Cz = (u16*)(ws + CZ_OFF);
  float* w8 = (float*)(ws + W8_OFF);
  u16*   xb = (u16*)(ws + XB_OFF);

  k_prep_router<<<10240, 256, 0, stream>>>(W, eA, eB, x, rw, Wz, Az, Bz, w8, xb);
  k_lora64<<<256, 256, 0, stream>>>(xb, Az, w8, Cz);
  k_main8<<<512, 512, 0, stream>>>(xb, Wz, Cz, Bz, out);
}

// Round 8
// 243.904 us; speedup vs baseline: 1.0377x; 1.0377x over previous
//
#include <hip/hip_runtime.h>
#include <stdint.h>

#define D_DIM 2048
#define OUT_DIM 2048
#define NTOK 16384
#define SCALING 1.0f
#define NT32 68   // 64 K-tiles (BK=32) of x@W^T + 4 LoRA-extension tiles

typedef unsigned short u16;
typedef __attribute__((ext_vector_type(8))) short s16x8;
typedef __attribute__((ext_vector_type(4))) float f32x4;

// ws layout (bytes)
#define WZ_OFF  0u           // W bf16 swizzled [2048 o][2048 d]
#define AZ_OFF  8388608u     // experts_A^T bf16 swizzled [128 er][2048 d]
#define BZ_OFF  8912896u     // experts_B^T bf16 swizzled [2048 o][128 er]
#define CZ_OFF  9437184u     // c bf16 swizzled [16384 t][128 er]
#define W8_OFF  13631488u    // router weights f32 [16384][8]
#define XB_OFF  14155776u    // x bf16 swizzled [16384][2048]
#define WS_BIG   81264640u

__device__ inline u16 f2bf(float f) {
  union { float f; uint32_t u; } v; v.f = f;
  uint32_t u = v.u;
  u += 0x7FFFu + ((u >> 16) & 1u);   // round-to-nearest-even
  return (u16)(u >> 16);
}

// 32-granule swizzle: within each 32-elem chunk, 8-elem granule s ^= (row>>1)&3
__device__ inline int swz32(int c, int row) {
  return (c & ~31) | (((((c >> 3) & 3) ^ ((row >> 1) & 3))) << 3) | (c & 7);
}

// ---- merged prep + router: cast/swizzle W,A^T,B^T; router logits + xb cast ---
__global__ __launch_bounds__(256) void k_prep_router(
    const float* __restrict__ W, const float* __restrict__ A,
    const float* __restrict__ Bf, const float* __restrict__ x,
    const float* __restrict__ rw,
    u16* __restrict__ Wz, u16* __restrict__ Az, u16* __restrict__ Bz,
    float* __restrict__ w8, u16* __restrict__ xb) {
  int bid = blockIdx.x;
  if (bid < 4096) {                      // W: 2048x2048 f32 -> bf16 swizzled
    int idx = bid * 256 + threadIdx.x;
    int o  = idx >> 9;
    int k0 = (idx & 511) * 4;            // 4-run, k0&7 in {0,4}: run preserved
    const float4 v = *(const float4*)&W[(size_t)o * D_DIM + k0];
    int dst = swz32(k0, o);
    uint32_t p0 = (uint32_t)f2bf(v.x) | ((uint32_t)f2bf(v.y) << 16);
    uint32_t p1 = (uint32_t)f2bf(v.z) | ((uint32_t)f2bf(v.w) << 16);
    *(uint2*)&Wz[(size_t)o * D_DIM + dst] = make_uint2(p0, p1);
    return;
  }
  if (bid < 5120) {                      // experts_A -> A^T swizzled
    int idx = (bid - 4096) * 256 + threadIdx.x;
    float v = A[idx];
    int r = idx & 15;
    int d = (idx >> 4) & 2047;
    int e = idx >> 15;
    int er = e * 16 + r;
    Az[(size_t)er * D_DIM + swz32(d, er)] = f2bf(v);
    return;
  }
  if (bid < 6144) {                      // experts_B -> B^T swizzled
    int idx = (bid - 5120) * 256 + threadIdx.x;
    float v = Bf[idx];
    int er = idx >> 11;
    int o  = idx & 2047;
    Bz[(size_t)o * 128 + swz32(er, o)] = f2bf(v);
    return;
  }
  // router + xb precast: one wave per token
  int lane = threadIdx.x & 63, wid = threadIdx.x >> 6;
  int t = (bid - 6144) * 4 + wid;
  const float* xr = x + (size_t)t * D_DIM;
  float4 xv[8];
#pragma unroll
  for (int j = 0; j < 8; ++j) xv[j] = *(const float4*)&xr[j * 256 + lane * 4];
#pragma unroll
  for (int j = 0; j < 8; ++j) {
    int c4 = j * 256 + lane * 4;
    int dst = swz32(c4, t);
    uint32_t p0 = (uint32_t)f2bf(xv[j].x) | ((uint32_t)f2bf(xv[j].y) << 16);
    uint32_t p1 = (uint32_t)f2bf(xv[j].z) | ((uint32_t)f2bf(xv[j].w) << 16);
    *(uint2*)&xb[(size_t)t * D_DIM + dst] = make_uint2(p0, p1);
  }
  float lg[8];
#pragma unroll
  for (int e = 0; e < 8; ++e) {
    float a = 0.f;
#pragma unroll
    for (int j = 0; j < 8; ++j) {
      float4 rv = *(const float4*)&rw[e * D_DIM + j * 256 + lane * 4];
      a = fmaf(xv[j].x, rv.x, a); a = fmaf(xv[j].y, rv.y, a);
      a = fmaf(xv[j].z, rv.z, a); a = fmaf(xv[j].w, rv.w, a);
    }
#pragma unroll
    for (int off = 32; off; off >>= 1) a += __shfl_xor(a, off, 64);
    lg[e] = a;
  }
  int i0 = 0;
#pragma unroll
  for (int e = 1; e < 8; ++e) if (lg[e] > lg[i0]) i0 = e;
  int i1 = (i0 == 0) ? 1 : 0;
#pragma unroll
  for (int e = 0; e < 8; ++e) if (e != i0 && lg[e] > lg[i1]) i1 = e;
  float e1 = expf(lg[i1] - lg[i0]);
  float inv = 1.f / (1.f + e1);
  float w0 = inv * SCALING, w1 = e1 * inv * SCALING;
  if (lane < 8)
    w8[(size_t)t * 8 + lane] = (lane == i0) ? w0 : (lane == i1) ? w1 : 0.f;
}

// ---------------- lora-down: c = (xb @ A_all) * w8 -> Cz (M-tile 64) ----------
// LDS as [buf][kk] sub-tiles of [rows][32] so the 32-granule swizzle is 2-way-free
__global__ __launch_bounds__(256) void k_lora64(const u16* __restrict__ xb,
                                                const u16* __restrict__ Az,
                                                const float* __restrict__ w8,
                                                u16* __restrict__ Cz) {
  __shared__ u16 Al[2][2][64 * 32];
  __shared__ u16 Bl[2][2][128 * 32];
  __shared__ float w8s[64 * 8];
  int tid = threadIdx.x, lane = tid & 63, wid = tid >> 6;
  int t0 = blockIdx.x * 64;
  w8s[tid] = w8[(size_t)t0 * 8 + tid];
  w8s[256 + tid] = w8[(size_t)t0 * 8 + 256 + tid];
  f32x4 acc[8];
#pragma unroll
  for (int n = 0; n < 8; ++n) acc[n] = (f32x4){0.f, 0.f, 0.f, 0.f};
  const int l15 = lane & 15;
  const int gA = (lane >> 4) ^ ((l15 >> 1) & 3);     // swizzled granule, per-lane
  const int arow = tid >> 2, c8 = (tid & 3) * 8;

  auto stage = [&](int kc, int buf) {
    if (kc > 31) kc = 31;
#pragma unroll
    for (int kk = 0; kk < 2; ++kk) {
      const u16* ga = xb + (size_t)(t0 + arow) * D_DIM + kc * 64 + kk * 32 + c8;
      __builtin_amdgcn_global_load_lds(
          (const __attribute__((address_space(1))) void*)ga,
          (__attribute__((address_space(3))) void*)(&Al[buf][kk][0] + tid * 8), 16, 0, 0);
#pragma unroll
      for (int i = 0; i < 2; ++i) {
        const u16* gb = Az + (size_t)(i * 64 + arow) * D_DIM + kc * 64 + kk * 32 + c8;
        __builtin_amdgcn_global_load_lds(
            (const __attribute__((address_space(1))) void*)gb,
            (__attribute__((address_space(3))) void*)(&Bl[buf][kk][0] + i * 2048 + tid * 8), 16, 0, 0);
      }
    }
  };

  stage(0, 0);
  asm volatile("s_waitcnt vmcnt(0)" ::: "memory");
  __builtin_amdgcn_s_barrier();
  const int aoff = (wid * 16 + l15) * 32 + gA * 8;
  for (int kc = 0; kc < 32; ++kc) {
    int cur = kc & 1;
    stage(kc + 1, cur ^ 1);
#pragma unroll
    for (int kk = 0; kk < 2; ++kk) {
      s16x8 af = *(const s16x8*)&Al[cur][kk][aoff];
#pragma unroll
      for (int nf = 0; nf < 8; ++nf) {
        s16x8 bf = *(const s16x8*)&Bl[cur][kk][(nf * 16 + l15) * 32 + gA * 8];
        acc[nf] = __builtin_amdgcn_mfma_f32_16x16x32_bf16(af, bf, acc[nf], 0, 0, 0);
      }
    }
    asm volatile("s_waitcnt vmcnt(0)" ::: "memory");
    __builtin_amdgcn_s_barrier();
  }
#pragma unroll
  for (int q = 0; q < 4; ++q) {
    int rloc = wid * 16 + (lane >> 4) * 4 + q;
#pragma unroll
    for (int nf = 0; nf < 8; ++nf) {
      int er = nf * 16 + l15;
      float v = acc[nf][q] * w8s[rloc * 8 + (er >> 4)];
      Cz[(size_t)(t0 + rloc) * 128 + swz32(er, rloc)] = f2bf(v);
    }
  }
}

// ------ 256^2 main GEMM: BK=32, 4-buffer rotation, pre-barrier pre-reads ------
__global__ __launch_bounds__(512, 2) void k_main32(const u16* __restrict__ xb,
                                                   const u16* __restrict__ Wz,
                                                   const u16* __restrict__ Cz,
                                                   const u16* __restrict__ Bz,
                                                   float* __restrict__ out) {
  __shared__ u16 AL[4][8192];   // 4 bufs x [256 rows][32 cols]
  __shared__ u16 BL[4][8192];
  const int tid = threadIdx.x, lane = tid & 63;
  const int wid = tid >> 6, wm = wid >> 2, wn = wid & 3;
  int bid = blockIdx.x;                     // 512 blocks, 512 % 8 == 0
  int swz = (bid & 7) * 64 + (bid >> 3);    // XCD-aware, bijective
  int mt = swz >> 3, nt = swz & 7;
  int t0 = mt * 256, o0 = nt * 256;
  const int l15 = lane & 15;
  const int gA = (lane >> 4) ^ ((l15 >> 1) & 3);
  const int aoff = (wm * 128 + l15) * 32 + gA * 8;   // frag i at +i*512
  const int boff = (wn * 64 + l15) * 32 + gA * 8;
  const int srow = tid >> 2, sc8 = (tid & 3) * 8;

  f32x4 acc[8][4];
#pragma unroll
  for (int m = 0; m < 8; ++m)
#pragma unroll
    for (int n = 0; n < 4; ++n) acc[m][n] = (f32x4){0.f, 0.f, 0.f, 0.f};
  s16x8 aA[8], bA[4], aB[8], bB[4];

  // stage tile t (clamped src) into buffer bufi: 2 A-loads + 2 B-loads
  auto stg = [&](int t, int bufi) {
    if (t > NT32 - 1) t = NT32 - 1;
    const u16 *sa, *sb; int lda, ldb, ca;
    if (t < 64) { sa = xb; lda = D_DIM; sb = Wz; ldb = D_DIM; ca = t * 32; }
    else        { sa = Cz; lda = 128;   sb = Bz; ldb = 128;   ca = (t - 64) * 32; }
#pragma unroll
    for (int i = 0; i < 2; ++i) {
      const u16* g = sa + (size_t)(t0 + i * 128 + srow) * lda + ca + sc8;
      __builtin_amdgcn_global_load_lds(
          (const __attribute__((address_space(1))) void*)g,
          (__attribute__((address_space(3))) void*)(&AL[bufi][0] + i * 4096 + tid * 8), 16, 0, 0);
    }
#pragma unroll
    for (int i = 0; i < 2; ++i) {
      const u16* g = sb + (size_t)(o0 + i * 128 + srow) * ldb + ca + sc8;
      __builtin_amdgcn_global_load_lds(
          (const __attribute__((address_space(1))) void*)g,
          (__attribute__((address_space(3))) void*)(&BL[bufi][0] + i * 4096 + tid * 8), 16, 0, 0);
    }
  };

#define RD(av, bv, bufi) do {                                           \
    const u16* ap_ = &AL[bufi][aoff];                                   \
    const u16* bp_ = &BL[bufi][boff];                                   \
    _Pragma("unroll") for (int i_ = 0; i_ < 8; ++i_)                    \
      av[i_] = *(const s16x8*)(ap_ + i_ * 512);                         \
    _Pragma("unroll") for (int j_ = 0; j_ < 4; ++j_)                    \
      bv[j_] = *(const s16x8*)(bp_ + j_ * 512);                         \
  } while (0)

#define MM(av, bv) do {                                                 \
    _Pragma("unroll") for (int mf_ = 0; mf_ < 8; ++mf_)                 \
      _Pragma("unroll") for (int nf_ = 0; nf_ < 4; ++nf_)               \
        acc[mf_][nf_] = __builtin_amdgcn_mfma_f32_16x16x32_bf16(        \
            av[mf_], bv[nf_], acc[mf_][nf_], 0, 0, 0);                  \
  } while (0)

  // prologue: tiles 0,1,2 staged; publish 0,1; preload regs from tile 0
  stg(0, 0); stg(1, 1); stg(2, 2);
  asm volatile("s_waitcnt vmcnt(4)" ::: "memory");   // tiles 0,1 landed
  __builtin_amdgcn_s_barrier();                       // ... and visible
  RD(aA, bA, 0);

  for (int jj = 0; jj < NT32; jj += 2) {
    // half 1: pre-read tile jj+1 (published); compute tile jj; stage jj+3
    RD(aB, bB, (jj + 1) & 3);
    MM(aA, bA);
    stg(jj + 3, (jj + 3) & 3);
    asm volatile("s_waitcnt vmcnt(4)" ::: "memory");  // tile jj+2 landed
    __builtin_amdgcn_s_barrier();                      // ... and visible
    // half 2: pre-read tile jj+2; compute tile jj+1; stage jj+4
    RD(aA, bA, (jj + 2) & 3);
    MM(aB, bB);
    stg(jj + 4, (jj + 4) & 3);
    asm volatile("s_waitcnt vmcnt(4)" ::: "memory");
    __builtin_amdgcn_s_barrier();
  }
  asm volatile("s_waitcnt vmcnt(0) lgkmcnt(0)" ::: "memory");
#undef RD
#undef MM

#pragma unroll
  for (int mf = 0; mf < 8; ++mf)
#pragma unroll
    for (int q = 0; q < 4; ++q) {
      int row = t0 + wm * 128 + mf * 16 + (lane >> 4) * 4 + q;
#pragma unroll
      for (int nf = 0; nf < 4; ++nf) {
        int col = o0 + wn * 64 + nf * 16 + l15;
        out[(size_t)row * OUT_DIM + col] = acc[mf][nf][q];
      }
    }
}

extern "C" void kernel_launch(void* const* d_in, const int* in_sizes, int n_in,
                              void* d_out, int out_size, void* d_ws, size_t ws_size,
                              hipStream_t stream) {
  const float* x  = (const float*)d_in[0];
  const float* W  = (const float*)d_in[1];
  const float* rw = (const float*)d_in[2];
  const float* eA = (const float*)d_in[3];
  const float* eB = (const float*)d_in[4];
  float* out = (float*)d_out;
  char* ws = (char*)d_ws;
  if (ws_size < WS_BIG) return;

  u16*   Wz = (u16*)(ws + WZ_OFF);
  u16*   Az = (u16*)(ws + AZ_OFF);
  u16*   Bz = (u16*)(ws + BZ_OFF);
  u16*   Cz = (u16*)(ws + CZ_OFF);
  float* w8 = (float*)(ws + W8_OFF);
  u16*   xb = (u16*)(ws + XB_OFF);

  k_prep_router<<<10240, 256, 0, stream>>>(W, eA, eB, x, rw, Wz, Az, Bz, w8, xb);
  k_lora64<<<256, 256, 0, stream>>>(xb, Az, w8, Cz);
  k_main32<<<512, 512, 0, stream>>>(xb, Wz, Cz, Bz, out);
}